// Round 14
// baseline (56.128 us; speedup 1.0000x reference)
//
#include <hip/hip_runtime.h>
#include <hip/hip_bf16.h>
#include <stdint.h>

// Attention (non-causal): B=2 H=16 S=2048 D=64, fp32 in/out.
// R14 = R11 + cross-period software pipeline (T15): period i computes
// QK^T(i) and PV(i-1) (independent MFMA streams) then SM(i); P (wp regs)
// carries across the barrier. V staging shifts one period later (stage K(i+1)
// and V(i) during period i) so V(i-1) stays resident while PV(i-1) runs —
// same double-buffers, same one-__syncthreads-per-period discipline.
// Rest = R11: 8 waves x 32 q-rows, KV parity split, 32x32x16 MFMA,
// fixed-offset softmax (exp2), in-register P via cvt_pk+permlane32_swap,
// gload_lds staging w/ XOR source swizzle, XCD block swizzle, fused prepass.
// (R12 reg-staged K: −24us, reverted. R13 pad: bank-conflict count is the
// structural 4cyc/b128 floor, not fixable — reverted to linear layout.)

#define B_ 2
#define H_ 16
#define S_ 2048
#define D_ 64
#define BH_ (B_ * H_)
#define QBLK 128
#define KVBLK 64
#define NKV (S_ / KVBLK)   // 32
#define NPER (NKV / 2)     // 16 periods, 2 tiles each

typedef __bf16 bf16_t;
typedef bf16_t bf16x8 __attribute__((ext_vector_type(8)));
typedef bf16_t bf16x4 __attribute__((ext_vector_type(4)));
typedef float f32x16 __attribute__((ext_vector_type(16)));
typedef uint32_t u32;

__device__ __forceinline__ f32x16 mfma32(bf16x8 a, bf16x8 b, f32x16 c) {
  return __builtin_amdgcn_mfma_f32_32x32x16_bf16(a, b, c, 0, 0, 0);
}

// pack two f32 -> u32 of 2 bf16 (lo in low 16 bits). No builtin on gfx950.
__device__ __forceinline__ u32 cvt_pk_bf16(float lo, float hi) {
  u32 r;
  asm("v_cvt_pk_bf16_f32 %0, %1, %2" : "=v"(r) : "v"(lo), "v"(hi));
  return r;
}

// v_permlane32_swap_b32 x, y: swaps x's lanes 32-63 with y's lanes 0-31.
__device__ __forceinline__ void swap32(u32& x, u32& y) {
  asm("v_permlane32_swap_b32 %0, %1" : "+v"(x), "+v"(y));
}

// async global->LDS, 16B per lane. LDS dest is wave-uniform base + lane*16.
__device__ __forceinline__ void gload_lds16(const bf16_t* g, bf16_t* l) {
  __builtin_amdgcn_global_load_lds(
      (const __attribute__((address_space(1))) unsigned int*)g,
      (__attribute__((address_space(3))) unsigned int*)l, 16, 0, 0);
}

// Fused prepass: z=0 -> K fp32 [bh][s][d] -> Kb bf16 (same layout);
//                z=1 -> V fp32 [bh][s][d] -> Vt bf16 [bh][d][s] (transpose).
__global__ void prepass_kernel(const float* __restrict__ k,
                               const float* __restrict__ v,
                               bf16_t* __restrict__ kb,
                               bf16_t* __restrict__ vt) {
  __shared__ float tile[64][65];
  const int bh = blockIdx.y, kt = blockIdx.x;
  if (blockIdx.z == 0) {
    const float* src = k + ((size_t)bh * S_ + (size_t)kt * 64) * D_;
    bf16_t* dst = kb + ((size_t)bh * S_ + (size_t)kt * 64) * D_;
#pragma unroll
    for (int i = 0; i < 4; ++i) {
      int idx = i * 256 + threadIdx.x;
      float4 x = ((const float4*)src)[idx];
      bf16x4 o = { (bf16_t)x.x, (bf16_t)x.y, (bf16_t)x.z, (bf16_t)x.w };
      *(bf16x4*)(dst + (size_t)idx * 4) = o;
    }
  } else {
    const float* vp = v + ((size_t)bh * S_ + (size_t)kt * 64) * D_;
    int r0 = threadIdx.x >> 4;
    int c4 = (threadIdx.x & 15) * 4;
#pragma unroll
    for (int p = 0; p < 4; ++p) {
      int r = r0 + p * 16;
      float4 x = *(const float4*)(vp + (size_t)r * D_ + c4);
      tile[r][c4 + 0] = x.x; tile[r][c4 + 1] = x.y;
      tile[r][c4 + 2] = x.z; tile[r][c4 + 3] = x.w;
    }
    __syncthreads();
    bf16_t* op = vt + (size_t)bh * D_ * S_ + (size_t)kt * 64;
#pragma unroll
    for (int p = 0; p < 4; ++p) {
      int d = r0 + p * 16;
      bf16x4 o = { (bf16_t)tile[c4 + 0][d], (bf16_t)tile[c4 + 1][d],
                   (bf16_t)tile[c4 + 2][d], (bf16_t)tile[c4 + 3][d] };
      *(bf16x4*)(op + (size_t)d * S_ + c4) = o;
    }
  }
}

// Main kernel. 512 threads = 8 waves; wave (wq, wkv) owns q-rows wq*32..+31
// and KV tiles of parity wkv. 32x32x16 MFMA layouts (m74/m101):
//   A: lane holds A[lane&31][(lane>>5)*8 + j]; B: B[(lane>>5)*8+j][lane&31]
//   C/D: lane holds D[(reg&3) + 8*(reg>>2) + 4*(lane>>5)][lane&31]
// Swapped QK^T: S^T[kv][q] = mfma(A=K, B=Q^T) -> P per-lane for q = lane&31.
// PV transposed: O^T[d][q] = mfma(A=V^T, B=P^T); B-frag slot (hi,j) for
// k-step kt2 holds kv = 16*kt2 + 8*hi + j via the permlane32 half-exchange.
// Pipeline: period i = {stage K(i+1), stage V(i), QK^T(i), PV(i-1), SM(i)}.
// K-pair (i&1)*2 read @i, written @i+1-staging -> disjoint. V-pair (i&1)*2
// written @i, read @i+1 (PV(i)), rewritten @i+2 -> disjoint. wp regs carry
// P across the barrier.
// XCD swizzle: bh = 4*(bid&7) + ((bid>>3)>>4), qt = (bid>>3)&15 (bijective).
__global__ __launch_bounds__(512, 4) void attn_kernel(
    const float* __restrict__ q, const bf16_t* __restrict__ kb,
    const bf16_t* __restrict__ vt, float* __restrict__ out) {
  const int bid = blockIdx.x;
  const int g = bid >> 3;
  const int bh = 4 * (bid & 7) + (g >> 4);
  const int qt = g & 15;
  const int tid = threadIdx.x;
  const int wid = tid >> 6;
  const int lane = tid & 63;
  const int wq = wid & 3;    // q-group
  const int wkv = wid >> 2;  // kv parity group
  const int l31 = lane & 31; // q column (QK^T) / row index
  const int hi = lane >> 5;  // lane half

  // 64 KB: K bufs [4][64][64] + V bufs [4][64][64]; epilogue aliases front.
  __shared__ __align__(16) char smem[65536];
  bf16_t* kbuf = (bf16_t*)smem;            // 4 x 4096 elems
  bf16_t* vbuf = (bf16_t*)(smem + 32768);  // 4 x 4096 elems
  float* epi = (float*)smem;               // [4][64][33] = 33.8 KB (aliases)

  const bf16_t* kp = kb + (size_t)bh * S_ * D_;
  const bf16_t* vp = vt + (size_t)bh * D_ * S_;

  // staging geometry: thread covers 16B chunk tid of each 8KB tile
  const int srow = tid >> 3;
  const int scol = (tid & 7) ^ (srow & 7);  // XOR chunk swizzle (source side)
  const int kofs = srow * D_ + scol * 8;
  const size_t vofs = (size_t)srow * S_ + scol * 8;
  const int ldst = wid * 512;  // elems, wave-uniform dest (wave covers 512)

  // Q B-fragments: lane holds Q[qrow][ks*16 + hi*8 + j] * 0.125*log2(e)
  const float qscale = 0.125f * 1.4426950408889634f;
  const int qrow = qt * QBLK + wq * 32 + l31;
  const float* qpr = q + ((size_t)bh * S_ + qrow) * D_;
  bf16x8 bq[4];
#pragma unroll
  for (int ks = 0; ks < 4; ++ks) {
    const float* p = qpr + ks * 16 + hi * 8;
    float4 x0 = *(const float4*)(p);
    float4 x1 = *(const float4*)(p + 4);
    bf16x8 a;
    a[0] = (bf16_t)(x0.x * qscale); a[1] = (bf16_t)(x0.y * qscale);
    a[2] = (bf16_t)(x0.z * qscale); a[3] = (bf16_t)(x0.w * qscale);
    a[4] = (bf16_t)(x1.x * qscale); a[5] = (bf16_t)(x1.y * qscale);
    a[6] = (bf16_t)(x1.z * qscale); a[7] = (bf16_t)(x1.w * qscale);
    bq[ks] = a;
  }

  float lsum = 0.f;
  f32x16 o0, o1;
#pragma unroll
  for (int r = 0; r < 16; ++r) { o0[r] = 0.f; o1[r] = 0.f; }

  // prologue: stage K tiles 0,1 into K-pair 0
#pragma unroll
  for (int par = 0; par < 2; ++par)
    gload_lds16(kp + (size_t)par * (KVBLK * D_) + kofs, kbuf + par * 4096 + ldst);
  __syncthreads();

  u32 wp[2][8];  // P fragments (post-swap), carried across the barrier

  for (int i = 0; i < NPER; ++i) {
    // stage K(i+1) into the other K-pair; stage V(i) into V-pair (i&1)
    if (i + 1 < NPER) {
      const int nb = ((i + 1) & 1) * 2;
#pragma unroll
      for (int par = 0; par < 2; ++par)
        gload_lds16(kp + (size_t)(2 * (i + 1) + par) * (KVBLK * D_) + kofs,
                    kbuf + (nb + par) * 4096 + ldst);
    }
    {
      const int vb = (i & 1) * 2;
#pragma unroll
      for (int par = 0; par < 2; ++par)
        gload_lds16(vp + (size_t)(2 * i + par) * KVBLK + vofs,
                    vbuf + (vb + par) * 4096 + ldst);
    }

    const bf16_t* kt_ = kbuf + ((i & 1) * 2 + wkv) * 4096;

    // QK^T(i): S^T[32 kv][32 q] per sub, 8 MFMAs
    f32x16 sv0, sv1;
#pragma unroll
    for (int r = 0; r < 16; ++r) { sv0[r] = 0.f; sv1[r] = 0.f; }
#pragma unroll
    for (int ks = 0; ks < 4; ++ks) {
      const int row0 = l31;
      const int ch0 = (2 * ks + hi) ^ (row0 & 7);
      bf16x8 a0 = *(const bf16x8*)(kt_ + row0 * D_ + ch0 * 8);
      sv0 = mfma32(a0, bq[ks], sv0);
      const int row1 = 32 + l31;
      const int ch1 = (2 * ks + hi) ^ (row1 & 7);
      bf16x8 a1 = *(const bf16x8*)(kt_ + row1 * D_ + ch1 * 8);
      sv1 = mfma32(a1, bq[ks], sv1);
    }

    // PV(i-1): independent MFMA stream on wp + V-pair ((i-1)&1)*2
    if (i > 0) {
      const bf16_t* vt_ = vbuf + (((i + 1) & 1) * 2 + wkv) * 4096;
#pragma unroll
      for (int sub = 0; sub < 2; ++sub)
#pragma unroll
        for (int kt2 = 0; kt2 < 2; ++kt2) {
          union { u32 u[4]; bf16x8 v; } pb;
          pb.u[0] = wp[sub][4 * kt2 + 0]; pb.u[1] = wp[sub][4 * kt2 + 1];
          pb.u[2] = wp[sub][4 * kt2 + 2]; pb.u[3] = wp[sub][4 * kt2 + 3];
          const int row = l31;
          const int ch = (4 * sub + 2 * kt2 + hi) ^ (row & 7);
          bf16x8 a = *(const bf16x8*)(vt_ + row * KVBLK + ch * 8);
          o0 = mfma32(a, pb.v, o0);
          const int rowb = 32 + l31;
          const int chb = (4 * sub + 2 * kt2 + hi) ^ (rowb & 7);
          bf16x8 ab = *(const bf16x8*)(vt_ + rowb * KVBLK + chb * 8);
          o1 = mfma32(ab, pb.v, o1);
        }
    }

    // SM(i): exp2 + pack + half-exchange -> wp (VALU; overlaps PV's MFMAs)
#pragma unroll
    for (int sub = 0; sub < 2; ++sub) {
      const f32x16 sv = sub ? sv1 : sv0;
#pragma unroll
      for (int b = 0; b < 4; ++b) {
        float e0 = __builtin_amdgcn_exp2f(sv[4 * b + 0]);
        float e1 = __builtin_amdgcn_exp2f(sv[4 * b + 1]);
        float e2 = __builtin_amdgcn_exp2f(sv[4 * b + 2]);
        float e3 = __builtin_amdgcn_exp2f(sv[4 * b + 3]);
        lsum += (e0 + e1) + (e2 + e3);
        wp[sub][2 * b + 0] = cvt_pk_bf16(e0, e1);
        wp[sub][2 * b + 1] = cvt_pk_bf16(e2, e3);
      }
#pragma unroll
      for (int kt2 = 0; kt2 < 2; ++kt2) {
        swap32(wp[sub][4 * kt2 + 0], wp[sub][4 * kt2 + 2]);
        swap32(wp[sub][4 * kt2 + 1], wp[sub][4 * kt2 + 3]);
      }
    }

    // barrier: drains vmcnt (staged tiles ready) + all waves done with cur
    __syncthreads();
  }

  // final PV(NPER-1): V-pair ((NPER-1)&1)*2 = 2
  {
    const bf16_t* vt_ = vbuf + (2 + wkv) * 4096;
#pragma unroll
    for (int sub = 0; sub < 2; ++sub)
#pragma unroll
      for (int kt2 = 0; kt2 < 2; ++kt2) {
        union { u32 u[4]; bf16x8 v; } pb;
        pb.u[0] = wp[sub][4 * kt2 + 0]; pb.u[1] = wp[sub][4 * kt2 + 1];
        pb.u[2] = wp[sub][4 * kt2 + 2]; pb.u[3] = wp[sub][4 * kt2 + 3];
        const int row = l31;
        const int ch = (4 * sub + 2 * kt2 + hi) ^ (row & 7);
        bf16x8 a = *(const bf16x8*)(vt_ + row * KVBLK + ch * 8);
        o0 = mfma32(a, pb.v, o0);
        const int rowb = 32 + l31;
        const int chb = (4 * sub + 2 * kt2 + hi) ^ (rowb & 7);
        bf16x8 ab = *(const bf16x8*)(vt_ + rowb * KVBLK + chb * 8);
        o1 = mfma32(ab, pb.v, o1);
      }
  }

  // ---- epilogue: combine kv-groups (pure addition: fixed-offset softmax)
  if (wkv == 1) {
    float* e = epi + ((size_t)wq * 64 + lane) * 33;
#pragma unroll
    for (int r = 0; r < 16; ++r) { e[r] = o0[r]; e[16 + r] = o1[r]; }
    e[32] = lsum;
  }
  __syncthreads();
  if (wkv == 0) {
    const float* e = epi + ((size_t)wq * 64 + lane) * 33;
#pragma unroll
    for (int r = 0; r < 16; ++r) { o0[r] += e[r]; o1[r] += e[16 + r]; }
    lsum += e[32];
    float ltot = lsum + __shfl_xor(lsum, 32, 64);
    float inv = 1.f / ltot;
    float* op = out + ((size_t)bh * S_ + qrow) * D_;
    // lane holds O^T[d = dblk*32 + 8b + 4hi + a][q = l31], a=0..3 consecutive
#pragma unroll
    for (int b = 0; b < 4; ++b) {
      float4 w0 = { o0[4 * b + 0] * inv, o0[4 * b + 1] * inv,
                    o0[4 * b + 2] * inv, o0[4 * b + 3] * inv };
      *(float4*)(op + 8 * b + 4 * hi) = w0;
      float4 w1 = { o1[4 * b + 0] * inv, o1[4 * b + 1] * inv,
                    o1[4 * b + 2] * inv, o1[4 * b + 3] * inv };
      *(float4*)(op + 32 + 8 * b + 4 * hi) = w1;
    }
  }
}

extern "C" void kernel_launch(void* const* d_in, const int* in_sizes, int n_in,
                              void* d_out, int out_size, void* d_ws, size_t ws_size,
                              hipStream_t stream) {
  const float* q = (const float*)d_in[0];
  const float* k = (const float*)d_in[1];
  const float* v = (const float*)d_in[2];
  float* out = (float*)d_out;

  // workspace: Kb (bf16 [BH][S][D]) + Vt (bf16 [BH][D][S]) = 16 MiB total
  bf16_t* kb = (bf16_t*)d_ws;
  bf16_t* vt = kb + (size_t)BH_ * S_ * D_;

  prepass_kernel<<<dim3(S_ / 64, BH_, 2), 256, 0, stream>>>(k, v, kb, vt);
  attn_kernel<<<dim3(BH_ * (S_ / QBLK)), 512, 0, stream>>>(q, kb, vt, out);
}